// Round 1
// 14965.123 us; speedup vs baseline: 1.0802x; 1.0802x over previous
//
#include <hip/hip_runtime.h>
#include <math.h>

#define NSYMB  40000
#define NMODES 256
#define LEAD   20000
#define UF     8      // prefetch/scheduling window: 8 steps per straight-line block

// glibc hypotf equivalent: exact double sum, sqrt, single round to f32 (CR)
static __device__ __forceinline__ float crhypotf(float a, float b) {
    const double da = (double)a, db = (double)b;
    return (float)sqrt(da * da + db * db);
}

// Branchless EXACT C-fmodf(xf, f32(pi/2)) for |xf| <~ 1e4 (here |xf| <= ~25).
// fmodf is an exact IEEE op; we reproduce it: q = trunc(x/y) from a CR f64
// divide is off by at most 1 from the true trunc, fma(-q,y,x) is the exact
// remainder candidate, one conditional +-y restores |r|<y with sign-of-
// dividend semantics. Only difference vs libm: +0 instead of -0 on an exact
// zero remainder of a negative dividend — unobservable downstream (rm<0 is
// false for both; ddmod = +-0 - P4f = -P4f for both).
static __device__ __forceinline__ float fmod_p2_exact(float xf) {
    const double y = (double)1.57079632679489661923f;  // f64 of f32(pi/2)
    const double x = (double)xf;
    const double q = __builtin_trunc(x / y);
    double r = __builtin_fma(-q, y, x);                // exact x - q*y
    r = (x >= 0.0) ? ((r < 0.0) ? r + y : ((r >= y) ? r - y : r))
                   : ((r > 0.0) ? r - y : ((r <= -y) ? r + y : r));
    return (float)r;
}

// Correctly-rounded f32 sincos via bounded-range f64 eval (fdlibm-style),
// BRANCHLESS. |x| < 1e6 always here (phi random-walks to ~1e2); 33-bit
// Cody-Waite pio2_1 keeps fma(-fn,pio2_1,x) exact. The old |x|>1e6 libm
// fallback never fired (author-verified) — removed so the step body is one
// basic block; removing a never-executed path cannot change trajectory bits.
// Quadrant dispatch is now cndmask + exact negation: identical values to the
// old if/else chain without the 4-way divergent exec-mask regions.
static __device__ __forceinline__ void cr_sincosf_nb(double x, float& sf, float& cf) {
    const double invpio2 = 6.36619772367581382433e-01;
    const double pio2_1  = 1.57079632673412561417e+00;   // 33 bits of pi/2
    const double pio2_1t = 6.07710050650619224932e-11;   // pi/2 - pio2_1
    const double fn = __builtin_rint(x * invpio2);
    const double rr = __builtin_fma(-fn, pio2_1, x);     // exact
    const double yy = rr - fn * pio2_1t;
    const double z  = yy * yy;
    double ps = __builtin_fma(z, 1.58969099521155010221e-10, -2.50507602534068634195e-08);
    ps = __builtin_fma(z, ps,  2.75573137070700676789e-06);
    ps = __builtin_fma(z, ps, -1.98412698298579493134e-04);
    ps = __builtin_fma(z, ps,  8.33333333332248946124e-03);
    ps = __builtin_fma(z, ps, -1.66666666666666324348e-01);
    const double sv = __builtin_fma(yy * z, ps, yy);
    double pc = __builtin_fma(z, -1.13596475577881948265e-11, 2.08757232129817482790e-09);
    pc = __builtin_fma(z, pc, -2.75573143513906633035e-07);
    pc = __builtin_fma(z, pc,  2.48015872894767294178e-05);
    pc = __builtin_fma(z, pc, -1.38888888888741095749e-03);
    pc = __builtin_fma(z, pc,  4.16666666666666019037e-02);
    const double hz = 0.5 * z;
    const double w1 = 1.0 - hz;
    const double cv = w1 + (((1.0 - w1) - hz) + z * (z * pc)); // fdlibm careful form
    const int n = ((int)fn) & 3;
    const float S = (float)sv, C = (float)cv;
    const bool sw = (n & 1) != 0;
    const float sa = sw ? C : S;                 // n=0:(S,C) 1:(C,-S) 2:(-S,-C) 3:(-C,S)
    const float ca = sw ? S : C;
    sf = (n & 2) ? -sa : sa;
    cf = ((n + 1) & 2) ? -ca : ca;
}

// One PLL step — bit-identical trajectory to the passing R5 kernel.
// All common-path branches eliminated:
//  - unwrap: branchless exact fmod + select on cum (old divergent region
//    executed ~85% of wave-steps because ANY of 64 lanes with |dd|>pi/4
//    triggered it; now it is straight-line and schedulable into chain bubbles)
//  - DD decision: fast path computed unconditionally (bit-equal to the
//    numpy-literal path outside the 1e-4 bisector band, proven previously);
//    literal path under a wave-uniform __ballot skip (~3% of steps).
template<bool PILOT>
static __device__ __forceinline__ void pll_step(
    int t, int idx, float yre, float yim, float txr, float txi,
    float Kv, const float* Lf,
    float& phi, float& prev, float& cum, float* __restrict__ theta_out)
{
#pragma clang fp contract(off)
    const float P2f  = 1.57079632679489661923f;  // f32(pi/2)
    const float P4f  = 0.78539816339744830961f;  // f32(pi/4)
    const float QTHf = 0.63245553203367588f;     // bisector 2/sqrt(10)

    // ---- unwrap bookkeeping on pre-update phase (off the phi chain) ----
    const float th = phi;
    const float dd = th - prev;
    float rm = fmod_p2_exact(dd + P4f);
    rm = (rm < 0.0f) ? rm + P2f : rm;            // numpy floor-mod
    float ddmod = rm - P4f;
    ddmod = (ddmod == -P4f && dd > 0.0f) ? P4f : ddmod;
    const bool take = (t > 0) && !(fabsf(dd) < P4f);
    cum = take ? cum + (ddmod - dd) : cum;       // select old cum when not taken
    prev = th;
    theta_out[idx] = th + cum;

    // ---- forward: e=(cos,sin) CR f32; z = y*e (numpy c64 mul, no FMA) ----
    float s, c;
    cr_sincosf_nb((double)phi, s, c);
    const float zre = (yre * c) - (yim * s);
    const float zim = (yre * s) + (yim * c);

    // ---- reverse-mode AD chain: ct_z = (A, B) ----
    float A, B;
    if (PILOT) {
        const float wre = zre - txr;
        const float wim = zim - txi;
        A = 2.0f * wre;
        B = -(2.0f * wim);
    } else {
        // fast path, always computed (bit-equal to literal path off-band)
        const float tr = (zre < 0.0f) ? ((zre < -QTHf) ? Lf[0] : Lf[1])
                                      : ((zre <  QTHf) ? Lf[2] : Lf[3]);
        const float ti = (zim < 0.0f) ? ((zim < -QTHf) ? Lf[0] : Lf[1])
                                      : ((zim <  QTHf) ? Lf[2] : Lf[3]);
        const float wre0 = zre - tr;
        const float wim0 = zim - ti;
        A = 2.0f * wre0;
        B = -(2.0f * wim0);
        const float ar = fabsf(zre), ai = fabsf(zim);
        const float mr = fminf(fabsf(ar - QTHf), ar);
        const float mi = fminf(fabsf(ai - QTHf), ai);
        const bool slow = !(mr > 1e-4f && mi > 1e-4f);
        if (__builtin_expect(__ballot(slow) != 0ULL, 0)) {
            if (slow) {
                // numpy-literal path (R5 verbatim): 16-point argmin + tie-average
                float dv[16], rv[16], wres[16], wims[16];
                float dmin = __builtin_inff();
                for (int k = 0; k < 16; ++k) {
                    const float wre = zre - Lf[k >> 2];
                    const float wim = zim - Lf[k & 3];
                    const float r = crhypotf(wre, wim);
                    const float d = r * r;
                    wres[k] = wre; wims[k] = wim; rv[k] = r; dv[k] = d;
                    dmin = fminf(dmin, d);
                }
                int cnt = 0;
                for (int k = 0; k < 16; ++k) cnt += (dv[k] == dmin) ? 1 : 0;
                if (cnt == 1) {
                    int j = 0;
                    for (int k = 0; k < 16; ++k) if (dv[k] == dmin) j = k;
                    A = 2.0f * wres[j];
                    B = -(2.0f * wims[j]);
                } else {
                    const float ctd = 1.0f / (float)cnt;
                    float sa = 0.0f, sb = 0.0f;
                    for (int k = 0; k < 16; ++k) {
                        if (dv[k] == dmin) {
                            const float ctr  = (2.0f * rv[k]) * ctd;
                            const float ctm2 = ctr / rv[k];
                            sa += (ctm2 * wres[k]);
                            sb += -(ctm2 * wims[k]);
                        }
                    }
                    A = sa; B = sb;
                }
            }
        }
    }
    // ct_e = mul(ct_z, y); ct_v = mul(ct_e, e); gk = -Im(ct_v)
    const float ct_e_re = (A * yre) - (B * yim);
    const float ct_e_im = (A * yim) + (B * yre);
    const float ct_v_im = (ct_e_re * s) + (ct_e_im * c);
    const float gk = -ct_v_im;
    phi = phi - (Kv * gk);
}

__global__ __launch_bounds__(64)
void ddpll_seq(const float* __restrict__ ei_re,
               const float* __restrict__ ei_im,
               const float* __restrict__ tx_re,
               const float* __restrict__ tx_im,
               const float* __restrict__ eta,
               float* __restrict__ out)
{
#pragma clang fp contract(off)
    const int m = blockIdx.x * 64 + threadIdx.x;   // mode 0..255
    const float Kv = (float)tanh((double)eta[0]);  // CR f32 tanh

    const double s10 = sqrt(10.0);
    float Lf[4];
    Lf[0] = (float)(-3.0 / s10); Lf[1] = (float)(-1.0 / s10);
    Lf[2] = (float)( 1.0 / s10); Lf[3] = (float)( 3.0 / s10);

    float phi = 0.0f, prev = 0.0f, cum = 0.0f;
    float* __restrict__ theta_out = out + (size_t)2 * NSYMB * NMODES;

    // ================= phase 1: pilot (t < LEAD) =================
    float pyr[UF], pyi[UF], pxr[UF], pxi[UF];
#pragma unroll
    for (int j = 0; j < UF; ++j) {
        const int idx = j * NMODES + m;
        pyr[j] = ei_re[idx]; pyi[j] = ei_im[idx];
        pxr[j] = tx_re[idx]; pxi[j] = tx_im[idx];
    }
    for (int tb = 0; tb < LEAD; tb += UF) {
        float yr[UF], yi[UF], xr[UF], xi[UF];
#pragma unroll
        for (int j = 0; j < UF; ++j) { yr[j]=pyr[j]; yi[j]=pyi[j]; xr[j]=pxr[j]; xi[j]=pxi[j]; }
        const int nb = tb + UF;
        // branchless prefetch: rows LEAD..LEAD+UF-1 are valid memory (over-read
        // at the final block is harmless and removes the per-block branch)
#pragma unroll
        for (int j = 0; j < UF; ++j) {
            const int idx = (nb + j) * NMODES + m;
            pyr[j] = ei_re[idx]; pyi[j] = ei_im[idx];
            pxr[j] = tx_re[idx]; pxi[j] = tx_im[idx];
        }
#pragma unroll
        for (int j = 0; j < UF; ++j)
            pll_step<true>(tb + j, (tb + j) * NMODES + m, yr[j], yi[j], xr[j], xi[j],
                           Kv, Lf, phi, prev, cum, theta_out);
    }

    // ================= phase 2: decision-directed =================
#pragma unroll
    for (int j = 0; j < UF; ++j) {
        const int idx = (LEAD + j) * NMODES + m;
        pyr[j] = ei_re[idx]; pyi[j] = ei_im[idx];
    }
    for (int tb = LEAD; tb < NSYMB; tb += UF) {
        float yr[UF], yi[UF];
#pragma unroll
        for (int j = 0; j < UF; ++j) { yr[j]=pyr[j]; yi[j]=pyi[j]; }
        const int nb = tb + UF;
#pragma unroll
        for (int j = 0; j < UF; ++j) {            // branchless prefetch, index-clamped
            const int tt = (nb + j < NSYMB) ? (nb + j) : (NSYMB - 1);
            const int idx = tt * NMODES + m;
            pyr[j] = ei_re[idx]; pyi[j] = ei_im[idx];
        }
#pragma unroll
        for (int j = 0; j < UF; ++j)
            pll_step<false>(tb + j, (tb + j) * NMODES + m, yr[j], yi[j], 0.0f, 0.0f,
                            Kv, Lf, phi, prev, cum, theta_out);
    }
}

// Parallel epilogue: Eo = Ei * exp(i * theta_unwrapped)  (err ~1e-6 << thr)
__global__ __launch_bounds__(256)
void ddpll_rot(const float* __restrict__ ei_re,
               const float* __restrict__ ei_im,
               float* __restrict__ out)
{
    const int idx = blockIdx.x * 256 + threadIdx.x;
    const float U = out[(size_t)2 * NSYMB * NMODES + idx];
    float su, cu;
    sincosf(U, &su, &cu);
    const float yre = ei_re[idx], yim = ei_im[idx];
    out[2 * idx]     = (yre * cu) - (yim * su);
    out[2 * idx + 1] = (yre * su) + (yim * cu);
}

extern "C" void kernel_launch(void* const* d_in, const int* in_sizes, int n_in,
                              void* d_out, int out_size, void* d_ws, size_t ws_size,
                              hipStream_t stream)
{
    (void)in_sizes; (void)n_in; (void)out_size; (void)d_ws; (void)ws_size;
    const float* ei_re = (const float*)d_in[0];
    const float* ei_im = (const float*)d_in[1];
    ddpll_seq<<<dim3(NMODES / 64), dim3(64), 0, stream>>>(
        ei_re, ei_im,
        (const float*)d_in[2],
        (const float*)d_in[3],
        (const float*)d_in[4],
        (float*)d_out);
    ddpll_rot<<<dim3(NSYMB * NMODES / 256), dim3(256), 0, stream>>>(
        ei_re, ei_im, (float*)d_out);
}

// Round 5
// 12926.021 us; speedup vs baseline: 1.2506x; 1.1578x over previous
//
#include <hip/hip_runtime.h>
#include <math.h>

#define NSYMB  40000
#define NMODES 256
#define LEAD   20000
#define UF     8      // scheduling window: 8 steps per block; unwrap pipelined 1 block behind

// glibc hypotf equivalent: exact double sum, sqrt, single round to f32 (CR)
static __device__ __forceinline__ float crhypotf(float a, float b) {
    const double da = (double)a, db = (double)b;
    return (float)sqrt(da * da + db * db);
}

// Branchless EXACT C-fmodf(xf, f32(pi/2)) WITHOUT an f64 division.
//   y  = f64 of f32(pi/2) (24-bit mantissa);  ry = correctly-rounded 1/y (const-folded).
//   q  = trunc(|x|*ry): equals the true trunc(|x|/y) or is off by exactly +-1
//        (rel err <= ~2^-52 * |x/y|, |x/y| << 2^40 here), both handled by the fixup.
//   r0 = fma(-q, y, |x|) is EXACT: q*y is a small-exponent product, |x| has a
//        24-bit mantissa, the difference fits f64 with margin.
//   The select chain restores the unique exact remainder in [0, y) — the final
//   value is independent of which admissible q we started from, so bits are
//   identical to the divide-based version. copysignf reproduces C fmod's
//   sign-of-dividend semantics including -0 (matching libm exactly).
static __device__ __forceinline__ float fmod_p2_exact(float xf) {
    const double y  = (double)1.57079632679489661923f;
    const double ry = 1.0 / ((double)1.57079632679489661923f);  // CR, compile-time
    const double ax = fabs((double)xf);
    const double q  = __builtin_trunc(ax * ry);
    double r = __builtin_fma(-q, y, ax);                 // exact |x| - q*y, in (-y, 2y)
    r = (r < 0.0) ? (r + y) : ((r >= y) ? (r - y) : r);  // exact fixup -> [0, y)
    return copysignf((float)r, xf);                      // (float)r exact (fmod thm)
}

// Correctly-rounded f32 sincos via bounded-range f64 eval (fdlibm-style),
// BRANCHLESS. |x| < 1e6 always here (phi random-walks to ~1e2); 33-bit
// Cody-Waite pio2_1 keeps fma(-fn,pio2_1,x) exact. Quadrant dispatch is
// cndmask + exact negation: identical values to an if/else chain.
static __device__ __forceinline__ void cr_sincosf_nb(double x, float& sf, float& cf) {
    const double invpio2 = 6.36619772367581382433e-01;
    const double pio2_1  = 1.57079632673412561417e+00;   // 33 bits of pi/2
    const double pio2_1t = 6.07710050650619224932e-11;   // pi/2 - pio2_1
    const double fn = __builtin_rint(x * invpio2);
    const double rr = __builtin_fma(-fn, pio2_1, x);     // exact
    const double yy = rr - fn * pio2_1t;
    const double z  = yy * yy;
    double ps = __builtin_fma(z, 1.58969099521155010221e-10, -2.50507602534068634195e-08);
    ps = __builtin_fma(z, ps,  2.75573137070700676789e-06);
    ps = __builtin_fma(z, ps, -1.98412698298579493134e-04);
    ps = __builtin_fma(z, ps,  8.33333333332248946124e-03);
    ps = __builtin_fma(z, ps, -1.66666666666666324348e-01);
    const double sv = __builtin_fma(yy * z, ps, yy);
    double pc = __builtin_fma(z, -1.13596475577881948265e-11, 2.08757232129817482790e-09);
    pc = __builtin_fma(z, pc, -2.75573143513906633035e-07);
    pc = __builtin_fma(z, pc,  2.48015872894767294178e-05);
    pc = __builtin_fma(z, pc, -1.38888888888741095749e-03);
    pc = __builtin_fma(z, pc,  4.16666666666666019037e-02);
    const double hz = 0.5 * z;
    const double w1 = 1.0 - hz;
    const double cv = w1 + (((1.0 - w1) - hz) + z * (z * pc)); // fdlibm careful form
    const int n = ((int)fn) & 3;
    const float S = (float)sv, C = (float)cv;
    const bool sw = (n & 1) != 0;
    const float sa = sw ? C : S;                 // n=0:(S,C) 1:(C,-S) 2:(-S,-C) 3:(-C,S)
    const float ca = sw ? S : C;
    sf = (n & 2) ? -sa : sa;
    cf = ((n + 1) & 2) ? -ca : ca;
}

// Rare decision-directed slow path (R5 verbatim): 16-point argmin + jax
// tie-average. noinline: keeps ~200 instrs OUT of the 8x-unrolled hot body
// (I-cache + scheduling window); call cost is irrelevant at ~3% wave-rate.
static __device__ __attribute__((noinline)) float2 dd_slow(float zre, float zim) {
#pragma clang fp contract(off)
    const double s10 = sqrt(10.0);
    float Lf[4];
    Lf[0] = (float)(-3.0 / s10); Lf[1] = (float)(-1.0 / s10);
    Lf[2] = (float)( 1.0 / s10); Lf[3] = (float)( 3.0 / s10);
    float dv[16], rv[16], wres[16], wims[16];
    float dmin = __builtin_inff();
#pragma unroll
    for (int k = 0; k < 16; ++k) {
        const float wre = zre - Lf[k >> 2];
        const float wim = zim - Lf[k & 3];
        const float r = crhypotf(wre, wim);
        const float d = r * r;
        wres[k] = wre; wims[k] = wim; rv[k] = r; dv[k] = d;
        dmin = fminf(dmin, d);
    }
    int cnt = 0;
#pragma unroll
    for (int k = 0; k < 16; ++k) cnt += (dv[k] == dmin) ? 1 : 0;
    float A, B;
    if (cnt == 1) {
        int j = 0;
#pragma unroll
        for (int k = 0; k < 16; ++k) if (dv[k] == dmin) j = k;
        A = 2.0f * wres[j];
        B = -(2.0f * wims[j]);
    } else {
        const float ctd = 1.0f / (float)cnt;
        float sa = 0.0f, sb = 0.0f;
#pragma unroll
        for (int k = 0; k < 16; ++k) {
            if (dv[k] == dmin) {
                const float ctr  = (2.0f * rv[k]) * ctd;
                const float ctm2 = ctr / rv[k];
                sa += (ctm2 * wres[k]);
                sb += -(ctm2 * wims[k]);
            }
        }
        A = sa; B = sb;
    }
    return make_float2(A, B);
}

// phi-chain only: advance phi by one PLL step (bit-identical ops/order to R1).
template<bool PILOT>
static __device__ __forceinline__ void phi_step(
    float yre, float yim, float txr, float txi,
    float Kv, const float* Lf, float& phi)
{
#pragma clang fp contract(off)
    const float QTHf = 0.63245553203367588f;     // bisector 2/sqrt(10)
    float s, c;
    cr_sincosf_nb((double)phi, s, c);
    const float zre = (yre * c) - (yim * s);
    const float zim = (yre * s) + (yim * c);
    float A, B;
    if (PILOT) {
        const float wre = zre - txr;
        const float wim = zim - txi;
        A = 2.0f * wre;
        B = -(2.0f * wim);
    } else {
        // fast path, always computed (bit-equal to literal path off-band, proven)
        const float tr = (zre < 0.0f) ? ((zre < -QTHf) ? Lf[0] : Lf[1])
                                      : ((zre <  QTHf) ? Lf[2] : Lf[3]);
        const float ti = (zim < 0.0f) ? ((zim < -QTHf) ? Lf[0] : Lf[1])
                                      : ((zim <  QTHf) ? Lf[2] : Lf[3]);
        const float wre0 = zre - tr;
        const float wim0 = zim - ti;
        A = 2.0f * wre0;
        B = -(2.0f * wim0);
        const float ar = fabsf(zre), ai = fabsf(zim);
        const float mr = fminf(fabsf(ar - QTHf), ar);
        const float mi = fminf(fabsf(ai - QTHf), ai);
        const bool slow = !(mr > 1e-4f && mi > 1e-4f);
        if (__builtin_expect(__ballot(slow) != 0ULL, 0)) {
            if (slow) { const float2 ab = dd_slow(zre, zim); A = ab.x; B = ab.y; }
        }
    }
    // ct_e = mul(ct_z, y); ct_v = mul(ct_e, e); gk = -Im(ct_v)
    const float ct_e_re = (A * yre) - (B * yim);
    const float ct_e_im = (A * yim) + (B * yre);
    const float ct_v_im = (ct_e_re * s) + (ct_e_im * c);
    const float gk = -ct_v_im;
    phi = phi - (Kv * gk);
}

// unwrap bookkeeping + theta emit for time t, given buffered pre-update phase.
// Independent of the phi chain -> pipelined one UF-block behind so the fmod
// latency hides in phi-chain bubbles. f32 ops/order identical to R1.
static __device__ __forceinline__ void unwrap_emit(
    int t, int m, float th, float& prev, float& cum, float* __restrict__ theta_out)
{
#pragma clang fp contract(off)
    const float P2f = 1.57079632679489661923f;   // f32(pi/2)
    const float P4f = 0.78539816339744830961f;   // f32(pi/4)
    const float dd = th - prev;
    float rm = fmod_p2_exact(dd + P4f);
    rm = (rm < 0.0f) ? rm + P2f : rm;            // numpy floor-mod
    float ddmod = rm - P4f;
    ddmod = (ddmod == -P4f && dd > 0.0f) ? P4f : ddmod;
    const bool take = (t > 0) && !(fabsf(dd) < P4f);
    cum = take ? cum + (ddmod - dd) : cum;
    prev = th;
    theta_out[t * NMODES + m] = th + cum;
}

__global__ __launch_bounds__(64)
void ddpll_seq(const float* __restrict__ ei_re,
               const float* __restrict__ ei_im,
               const float* __restrict__ tx_re,
               const float* __restrict__ tx_im,
               const float* __restrict__ eta,
               float* __restrict__ out)
{
#pragma clang fp contract(off)
    const int m = blockIdx.x * 64 + threadIdx.x;   // mode 0..255
    const float Kv = (float)tanh((double)eta[0]);  // CR f32 tanh

    const double s10 = sqrt(10.0);
    float Lf[4];
    Lf[0] = (float)(-3.0 / s10); Lf[1] = (float)(-1.0 / s10);
    Lf[2] = (float)( 1.0 / s10); Lf[3] = (float)( 3.0 / s10);

    float phi = 0.0f, prev = 0.0f, cum = 0.0f;
    float thb[UF];                                  // buffered pre-update phases
    float* __restrict__ theta_out = out + (size_t)2 * NSYMB * NMODES;

    // ================= phase 1: pilot (t < LEAD) =================
    float pyr[UF], pyi[UF], pxr[UF], pxi[UF];
#pragma unroll
    for (int j = 0; j < UF; ++j) {
        const int idx = j * NMODES + m;
        pyr[j] = ei_re[idx]; pyi[j] = ei_im[idx];
        pxr[j] = tx_re[idx]; pxi[j] = tx_im[idx];
    }
    // ---- block 0 peeled: phi steps only (no previous block to unwrap) ----
    {
        float yr[UF], yi[UF], xr[UF], xi[UF];
#pragma unroll
        for (int j = 0; j < UF; ++j) { yr[j]=pyr[j]; yi[j]=pyi[j]; xr[j]=pxr[j]; xi[j]=pxi[j]; }
#pragma unroll
        for (int j = 0; j < UF; ++j) {               // prefetch block 1
            const int idx = (UF + j) * NMODES + m;
            pyr[j] = ei_re[idx]; pyi[j] = ei_im[idx];
            pxr[j] = tx_re[idx]; pxi[j] = tx_im[idx];
        }
#pragma unroll
        for (int j = 0; j < UF; ++j) {
            thb[j] = phi;
            phi_step<true>(yr[j], yi[j], xr[j], xi[j], Kv, Lf, phi);
        }
    }
    for (int tb = UF; tb < LEAD; tb += UF) {
        float yr[UF], yi[UF], xr[UF], xi[UF];
#pragma unroll
        for (int j = 0; j < UF; ++j) { yr[j]=pyr[j]; yi[j]=pyi[j]; xr[j]=pxr[j]; xi[j]=pxi[j]; }
        const int nb = tb + UF;
        // branchless prefetch: rows LEAD..LEAD+UF-1 are valid memory (over-read
        // at the final block is harmless and removes the per-block branch)
#pragma unroll
        for (int j = 0; j < UF; ++j) {
            const int idx = (nb + j) * NMODES + m;
            pyr[j] = ei_re[idx]; pyi[j] = ei_im[idx];
            pxr[j] = tx_re[idx]; pxi[j] = tx_im[idx];
        }
#pragma unroll
        for (int j = 0; j < UF; ++j) {
            const float u = thb[j];                  // previous block's phase
            thb[j] = phi;
            unwrap_emit(tb - UF + j, m, u, prev, cum, theta_out);  // overlaps phi chain
            phi_step<true>(yr[j], yi[j], xr[j], xi[j], Kv, Lf, phi);
        }
    }

    // ================= phase 2: decision-directed =================
#pragma unroll
    for (int j = 0; j < UF; ++j) {
        const int idx = (LEAD + j) * NMODES + m;
        pyr[j] = ei_re[idx]; pyi[j] = ei_im[idx];
    }
    for (int tb = LEAD; tb < NSYMB; tb += UF) {
        float yr[UF], yi[UF];
#pragma unroll
        for (int j = 0; j < UF; ++j) { yr[j]=pyr[j]; yi[j]=pyi[j]; }
        const int nb = tb + UF;
#pragma unroll
        for (int j = 0; j < UF; ++j) {               // branchless prefetch, index-clamped
            const int tt = (nb + j < NSYMB) ? (nb + j) : (NSYMB - 1);
            const int idx = tt * NMODES + m;
            pyr[j] = ei_re[idx]; pyi[j] = ei_im[idx];
        }
#pragma unroll
        for (int j = 0; j < UF; ++j) {
            const float u = thb[j];                  // block tb-UF (crosses pilot/DD seam)
            thb[j] = phi;
            unwrap_emit(tb - UF + j, m, u, prev, cum, theta_out);
            phi_step<false>(yr[j], yi[j], 0.0f, 0.0f, Kv, Lf, phi);
        }
    }
    // ---- epilogue: unwrap the final block ----
#pragma unroll
    for (int j = 0; j < UF; ++j)
        unwrap_emit(NSYMB - UF + j, m, thb[j], prev, cum, theta_out);
}

// Parallel epilogue: Eo = Ei * exp(i * theta_unwrapped)  (err ~1e-6 << thr)
__global__ __launch_bounds__(256)
void ddpll_rot(const float* __restrict__ ei_re,
               const float* __restrict__ ei_im,
               float* __restrict__ out)
{
    const int idx = blockIdx.x * 256 + threadIdx.x;
    const float U = out[(size_t)2 * NSYMB * NMODES + idx];
    float su, cu;
    sincosf(U, &su, &cu);
    const float yre = ei_re[idx], yim = ei_im[idx];
    out[2 * idx]     = (yre * cu) - (yim * su);
    out[2 * idx + 1] = (yre * su) + (yim * cu);
}

extern "C" void kernel_launch(void* const* d_in, const int* in_sizes, int n_in,
                              void* d_out, int out_size, void* d_ws, size_t ws_size,
                              hipStream_t stream)
{
    (void)in_sizes; (void)n_in; (void)out_size; (void)d_ws; (void)ws_size;
    const float* ei_re = (const float*)d_in[0];
    const float* ei_im = (const float*)d_in[1];
    ddpll_seq<<<dim3(NMODES / 64), dim3(64), 0, stream>>>(
        ei_re, ei_im,
        (const float*)d_in[2],
        (const float*)d_in[3],
        (const float*)d_in[4],
        (float*)d_out);
    ddpll_rot<<<dim3(NSYMB * NMODES / 256), dim3(256), 0, stream>>>(
        ei_re, ei_im, (float*)d_out);
}

// Round 6
// 12392.146 us; speedup vs baseline: 1.3044x; 1.0431x over previous
//
#include <hip/hip_runtime.h>
#include <math.h>

#define NSYMB  40000
#define NMODES 256
#define LEAD   20000
#define UF     8      // scheduling/prefetch window

// glibc hypotf equivalent: exact double sum, sqrt, single round to f32 (CR)
static __device__ __forceinline__ float crhypotf(float a, float b) {
    const double da = (double)a, db = (double)b;
    return (float)sqrt(da * da + db * db);
}

// Branchless EXACT C-fmodf(xf, f32(pi/2)) WITHOUT an f64 division.
//   q = trunc(|x|*ry) equals the true trunc(|x|/y) or is off by exactly +-1;
//   fma(-q,y,|x|) is exact; the select chain restores the unique exact
//   remainder in [0,y) -> final bits are q-path-independent (== divide version).
static __device__ __forceinline__ float fmod_p2_exact(float xf) {
    const double y  = (double)1.57079632679489661923f;
    const double ry = 1.0 / ((double)1.57079632679489661923f);  // CR, compile-time
    const double ax = fabs((double)xf);
    const double q  = __builtin_trunc(ax * ry);
    double r = __builtin_fma(-q, y, ax);                 // exact |x| - q*y, in (-y, 2y)
    r = (r < 0.0) ? (r + y) : ((r >= y) ? (r - y) : r);  // exact fixup -> [0, y)
    return copysignf((float)r, xf);                      // (float)r exact (fmod thm)
}

// Correctly-rounded f32 sincos via bounded-range f64 eval (fdlibm-style),
// BRANCHLESS. |x| < 1e6 always here (phi random-walks to ~1e2); 33-bit
// Cody-Waite pio2_1 keeps fma(-fn,pio2_1,x) exact. Quadrant dispatch is
// cndmask + exact negation: identical values to an if/else chain.
static __device__ __forceinline__ void cr_sincosf_nb(double x, float& sf, float& cf) {
    const double invpio2 = 6.36619772367581382433e-01;
    const double pio2_1  = 1.57079632673412561417e+00;   // 33 bits of pi/2
    const double pio2_1t = 6.07710050650619224932e-11;   // pi/2 - pio2_1
    const double fn = __builtin_rint(x * invpio2);
    const double rr = __builtin_fma(-fn, pio2_1, x);     // exact
    const double yy = rr - fn * pio2_1t;
    const double z  = yy * yy;
    double ps = __builtin_fma(z, 1.58969099521155010221e-10, -2.50507602534068634195e-08);
    ps = __builtin_fma(z, ps,  2.75573137070700676789e-06);
    ps = __builtin_fma(z, ps, -1.98412698298579493134e-04);
    ps = __builtin_fma(z, ps,  8.33333333332248946124e-03);
    ps = __builtin_fma(z, ps, -1.66666666666666324348e-01);
    const double sv = __builtin_fma(yy * z, ps, yy);
    double pc = __builtin_fma(z, -1.13596475577881948265e-11, 2.08757232129817482790e-09);
    pc = __builtin_fma(z, pc, -2.75573143513906633035e-07);
    pc = __builtin_fma(z, pc,  2.48015872894767294178e-05);
    pc = __builtin_fma(z, pc, -1.38888888888741095749e-03);
    pc = __builtin_fma(z, pc,  4.16666666666666019037e-02);
    const double hz = 0.5 * z;
    const double w1 = 1.0 - hz;
    const double cv = w1 + (((1.0 - w1) - hz) + z * (z * pc)); // fdlibm careful form
    const int n = ((int)fn) & 3;
    const float S = (float)sv, C = (float)cv;
    const bool sw = (n & 1) != 0;
    const float sa = sw ? C : S;                 // n=0:(S,C) 1:(C,-S) 2:(-S,-C) 3:(-C,S)
    const float ca = sw ? S : C;
    sf = (n & 2) ? -sa : sa;
    cf = ((n + 1) & 2) ? -ca : ca;
}

// Rare decision-directed slow path (R5 verbatim): 16-point argmin + jax
// tie-average. noinline: keeps ~200 instrs OUT of the 8x-unrolled hot body.
static __device__ __attribute__((noinline)) float2 dd_slow(float zre, float zim) {
#pragma clang fp contract(off)
    const double s10 = sqrt(10.0);
    float Lf[4];
    Lf[0] = (float)(-3.0 / s10); Lf[1] = (float)(-1.0 / s10);
    Lf[2] = (float)( 1.0 / s10); Lf[3] = (float)( 3.0 / s10);
    float dv[16], rv[16], wres[16], wims[16];
    float dmin = __builtin_inff();
#pragma unroll
    for (int k = 0; k < 16; ++k) {
        const float wre = zre - Lf[k >> 2];
        const float wim = zim - Lf[k & 3];
        const float r = crhypotf(wre, wim);
        const float d = r * r;
        wres[k] = wre; wims[k] = wim; rv[k] = r; dv[k] = d;
        dmin = fminf(dmin, d);
    }
    int cnt = 0;
#pragma unroll
    for (int k = 0; k < 16; ++k) cnt += (dv[k] == dmin) ? 1 : 0;
    float A, B;
    if (cnt == 1) {
        int j = 0;
#pragma unroll
        for (int k = 0; k < 16; ++k) if (dv[k] == dmin) j = k;
        A = 2.0f * wres[j];
        B = -(2.0f * wims[j]);
    } else {
        const float ctd = 1.0f / (float)cnt;
        float sa = 0.0f, sb = 0.0f;
#pragma unroll
        for (int k = 0; k < 16; ++k) {
            if (dv[k] == dmin) {
                const float ctr  = (2.0f * rv[k]) * ctd;
                const float ctm2 = ctr / rv[k];
                sa += (ctm2 * wres[k]);
                sb += -(ctm2 * wims[k]);
            }
        }
        A = sa; B = sb;
    }
    return make_float2(A, B);
}

// phi-chain only: advance phi by one PLL step (bit-identical ops/order to R5).
template<bool PILOT>
static __device__ __forceinline__ void phi_step(
    float yre, float yim, float txr, float txi,
    float Kv, const float* Lf, float& phi)
{
#pragma clang fp contract(off)
    const float QTHf = 0.63245553203367588f;     // bisector 2/sqrt(10)
    float s, c;
    cr_sincosf_nb((double)phi, s, c);
    const float zre = (yre * c) - (yim * s);
    const float zim = (yre * s) + (yim * c);
    float A, B;
    if (PILOT) {
        const float wre = zre - txr;
        const float wim = zim - txi;
        A = 2.0f * wre;
        B = -(2.0f * wim);
    } else {
        // fast path, always computed (bit-equal to literal path off-band, proven)
        const float tr = (zre < 0.0f) ? ((zre < -QTHf) ? Lf[0] : Lf[1])
                                      : ((zre <  QTHf) ? Lf[2] : Lf[3]);
        const float ti = (zim < 0.0f) ? ((zim < -QTHf) ? Lf[0] : Lf[1])
                                      : ((zim <  QTHf) ? Lf[2] : Lf[3]);
        const float wre0 = zre - tr;
        const float wim0 = zim - ti;
        A = 2.0f * wre0;
        B = -(2.0f * wim0);
        const float ar = fabsf(zre), ai = fabsf(zim);
        const float mr = fminf(fabsf(ar - QTHf), ar);
        const float mi = fminf(fabsf(ai - QTHf), ai);
        const bool slow = !(mr > 1e-4f && mi > 1e-4f);
        if (__builtin_expect(__ballot(slow) != 0ULL, 0)) {
            if (slow) { const float2 ab = dd_slow(zre, zim); A = ab.x; B = ab.y; }
        }
    }
    // ct_e = mul(ct_z, y); ct_v = mul(ct_e, e); gk = -Im(ct_v)
    const float ct_e_re = (A * yre) - (B * yim);
    const float ct_e_im = (A * yim) + (B * yre);
    const float ct_v_im = (ct_e_re * s) + (ct_e_im * c);
    const float gk = -ct_v_im;
    phi = phi - (Kv * gk);
}

// Serial kernel: ONLY the phi recurrence + raw-phase store. Unwrap is evicted
// to the parallel ddpll_unwrapc + tiny ddpll_scan kernels (c_t depends only on
// th_t, th_{t-1}; cum is a pure f32 fold over c_t — computed later, bit-exactly).
__global__ __launch_bounds__(64)
void ddpll_seq(const float* __restrict__ ei_re,
               const float* __restrict__ ei_im,
               const float* __restrict__ tx_re,
               const float* __restrict__ tx_im,
               const float* __restrict__ eta,
               float* __restrict__ out)
{
#pragma clang fp contract(off)
    const int m = blockIdx.x * 64 + threadIdx.x;   // mode 0..255
    const float Kv = (float)tanh((double)eta[0]);  // CR f32 tanh

    const double s10 = sqrt(10.0);
    float Lf[4];
    Lf[0] = (float)(-3.0 / s10); Lf[1] = (float)(-1.0 / s10);
    Lf[2] = (float)( 1.0 / s10); Lf[3] = (float)( 3.0 / s10);

    float phi = 0.0f;
    float* __restrict__ th_out = out + (size_t)2 * NSYMB * NMODES;  // raw th

    // ================= phase 1: pilot (t < LEAD) =================
    float pyr[UF], pyi[UF], pxr[UF], pxi[UF];
#pragma unroll
    for (int j = 0; j < UF; ++j) {
        const int idx = j * NMODES + m;
        pyr[j] = ei_re[idx]; pyi[j] = ei_im[idx];
        pxr[j] = tx_re[idx]; pxi[j] = tx_im[idx];
    }
    for (int tb = 0; tb < LEAD; tb += UF) {
        float yr[UF], yi[UF], xr[UF], xi[UF];
#pragma unroll
        for (int j = 0; j < UF; ++j) { yr[j]=pyr[j]; yi[j]=pyi[j]; xr[j]=pxr[j]; xi[j]=pxi[j]; }
        const int nb = tb + UF;
        // branchless prefetch: rows LEAD..LEAD+UF-1 are valid memory (over-read
        // at the final block is harmless and removes the per-block branch)
#pragma unroll
        for (int j = 0; j < UF; ++j) {
            const int idx = (nb + j) * NMODES + m;
            pyr[j] = ei_re[idx]; pyi[j] = ei_im[idx];
            pxr[j] = tx_re[idx]; pxi[j] = tx_im[idx];
        }
#pragma unroll
        for (int j = 0; j < UF; ++j) {
            th_out[(tb + j) * NMODES + m] = phi;     // raw pre-update phase
            phi_step<true>(yr[j], yi[j], xr[j], xi[j], Kv, Lf, phi);
        }
    }

    // ================= phase 2: decision-directed =================
#pragma unroll
    for (int j = 0; j < UF; ++j) {
        const int idx = (LEAD + j) * NMODES + m;
        pyr[j] = ei_re[idx]; pyi[j] = ei_im[idx];
    }
    for (int tb = LEAD; tb < NSYMB; tb += UF) {
        float yr[UF], yi[UF];
#pragma unroll
        for (int j = 0; j < UF; ++j) { yr[j]=pyr[j]; yi[j]=pyi[j]; }
        const int nb = tb + UF;
#pragma unroll
        for (int j = 0; j < UF; ++j) {               // branchless prefetch, index-clamped
            const int tt = (nb + j < NSYMB) ? (nb + j) : (NSYMB - 1);
            const int idx = tt * NMODES + m;
            pyr[j] = ei_re[idx]; pyi[j] = ei_im[idx];
        }
#pragma unroll
        for (int j = 0; j < UF; ++j) {
            th_out[(tb + j) * NMODES + m] = phi;
            phi_step<false>(yr[j], yi[j], 0.0f, 0.0f, Kv, Lf, phi);
        }
    }
}

// Parallel unwrap-correction: c_t = take ? (ddmod - dd) : +0.0f.
// Identical f32/f64 ops as the original in-loop unwrap, on identical th bits.
__global__ __launch_bounds__(256)
void ddpll_unwrapc(const float* __restrict__ th, float* __restrict__ c)
{
#pragma clang fp contract(off)
    const float P2f = 1.57079632679489661923f;   // f32(pi/2)
    const float P4f = 0.78539816339744830961f;   // f32(pi/4)
    const int idx = blockIdx.x * 256 + threadIdx.x;   // t*NMODES + m
    float cv = 0.0f;                              // t==0: no correction
    if (idx >= NMODES) {
        const float thv  = th[idx];
        const float prev = th[idx - NMODES];
        const float dd = thv - prev;
        float rm = fmod_p2_exact(dd + P4f);
        rm = (rm < 0.0f) ? rm + P2f : rm;        // numpy floor-mod
        float ddmod = rm - P4f;
        ddmod = (ddmod == -P4f && dd > 0.0f) ? P4f : ddmod;
        const bool take = !(fabsf(dd) < P4f);
        cv = take ? (ddmod - dd) : 0.0f;
    }
    c[idx] = cv;
}

// Tiny serial scan: cum fold over c_t (bit-exact: adding +0.0f is the identity
// on cum, and cum is provably never -0), theta_t = th_t + cum_t written in
// place over the raw-th region. Chain = 1 f32 add/step -> ~250us.
__global__ __launch_bounds__(64)
void ddpll_scan(const float* __restrict__ c, float* __restrict__ th)
{
#pragma clang fp contract(off)
    const int m = blockIdx.x * 64 + threadIdx.x;   // mode 0..255
    float cum = 0.0f;
    float pc_[UF], pt_[UF];
#pragma unroll
    for (int j = 0; j < UF; ++j) {
        pc_[j] = c[j * NMODES + m];
        pt_[j] = th[j * NMODES + m];
    }
    for (int tb = 0; tb < NSYMB; tb += UF) {
        float cv[UF], tv[UF];
#pragma unroll
        for (int j = 0; j < UF; ++j) { cv[j]=pc_[j]; tv[j]=pt_[j]; }
        const int nb = tb + UF;
#pragma unroll
        for (int j = 0; j < UF; ++j) {               // branchless prefetch, clamped
            const int tt = (nb + j < NSYMB) ? (nb + j) : (NSYMB - 1);
            pc_[j] = c[tt * NMODES + m];
            pt_[j] = th[tt * NMODES + m];            // read-before-write on clamped tail
        }
#pragma unroll
        for (int j = 0; j < UF; ++j) {
            cum = cum + cv[j];                       // == original conditional update
            th[(tb + j) * NMODES + m] = tv[j] + cum;
        }
    }
}

// Parallel epilogue: Eo = Ei * exp(i * theta_unwrapped)  (err ~1e-6 << thr)
__global__ __launch_bounds__(256)
void ddpll_rot(const float* __restrict__ ei_re,
               const float* __restrict__ ei_im,
               float* __restrict__ out)
{
    const int idx = blockIdx.x * 256 + threadIdx.x;
    const float U = out[(size_t)2 * NSYMB * NMODES + idx];
    float su, cu;
    sincosf(U, &su, &cu);
    const float yre = ei_re[idx], yim = ei_im[idx];
    out[2 * idx]     = (yre * cu) - (yim * su);
    out[2 * idx + 1] = (yre * su) + (yim * cu);
}

extern "C" void kernel_launch(void* const* d_in, const int* in_sizes, int n_in,
                              void* d_out, int out_size, void* d_ws, size_t ws_size,
                              hipStream_t stream)
{
    (void)in_sizes; (void)n_in; (void)out_size; (void)d_ws; (void)ws_size;
    const float* ei_re = (const float*)d_in[0];
    const float* ei_im = (const float*)d_in[1];
    float* out = (float*)d_out;
    float* th  = out + (size_t)2 * NSYMB * NMODES;   // theta region (raw th first)
    float* c   = out;                                // Eo region reused as scratch for c

    ddpll_seq<<<dim3(NMODES / 64), dim3(64), 0, stream>>>(
        ei_re, ei_im,
        (const float*)d_in[2],
        (const float*)d_in[3],
        (const float*)d_in[4],
        out);
    ddpll_unwrapc<<<dim3(NSYMB * NMODES / 256), dim3(256), 0, stream>>>(th, c);
    ddpll_scan<<<dim3(NMODES / 64), dim3(64), 0, stream>>>(c, th);
    ddpll_rot<<<dim3(NSYMB * NMODES / 256), dim3(256), 0, stream>>>(
        ei_re, ei_im, out);
}

// Round 8
// 11878.375 us; speedup vs baseline: 1.3609x; 1.0433x over previous
//
#include <hip/hip_runtime.h>
#include <math.h>

#define NSYMB  40000
#define NMODES 256
#define LEAD   20000
#define UF     8      // seq scheduling/prefetch window
#define NM     (NSYMB * NMODES)

// glibc hypotf equivalent: exact double sum, sqrt, single round to f32 (CR)
static __device__ __forceinline__ float crhypotf(float a, float b) {
    const double da = (double)a, db = (double)b;
    return (float)sqrt(da * da + db * db);
}

// Branchless EXACT C-fmodf(xf, f32(pi/2)) WITHOUT an f64 division.
// q = trunc(|x|*ry) is the true quotient or +-1 off; fma(-q,y,|x|) is exact;
// the fixup restores the unique exact remainder in [0,y) -> bits identical
// to the divide-based version.
static __device__ __forceinline__ float fmod_p2_exact(float xf) {
    const double y  = (double)1.57079632679489661923f;
    const double ry = 1.0 / ((double)1.57079632679489661923f);  // CR, compile-time
    const double ax = fabs((double)xf);
    const double q  = __builtin_trunc(ax * ry);
    double r = __builtin_fma(-q, y, ax);                 // exact |x| - q*y, in (-y, 2y)
    r = (r < 0.0) ? (r + y) : ((r >= y) ? (r - y) : r);  // exact fixup -> [0, y)
    return copysignf((float)r, xf);                      // (float)r exact (fmod thm)
}

// Correctly-rounded f32 sincos via bounded-range f64 eval (fdlibm-style),
// BRANCHLESS. |x| < 1e6 always here; 33-bit Cody-Waite pio2_1 keeps
// fma(-fn,pio2_1,x) exact. Quadrant dispatch = cndmask + exact negation.
static __device__ __forceinline__ void cr_sincosf_nb(double x, float& sf, float& cf) {
    const double invpio2 = 6.36619772367581382433e-01;
    const double pio2_1  = 1.57079632673412561417e+00;   // 33 bits of pi/2
    const double pio2_1t = 6.07710050650619224932e-11;   // pi/2 - pio2_1
    const double fn = __builtin_rint(x * invpio2);
    const double rr = __builtin_fma(-fn, pio2_1, x);     // exact
    const double yy = rr - fn * pio2_1t;
    const double z  = yy * yy;
    double ps = __builtin_fma(z, 1.58969099521155010221e-10, -2.50507602534068634195e-08);
    ps = __builtin_fma(z, ps,  2.75573137070700676789e-06);
    ps = __builtin_fma(z, ps, -1.98412698298579493134e-04);
    ps = __builtin_fma(z, ps,  8.33333333332248946124e-03);
    ps = __builtin_fma(z, ps, -1.66666666666666324348e-01);
    const double sv = __builtin_fma(yy * z, ps, yy);
    double pc = __builtin_fma(z, -1.13596475577881948265e-11, 2.08757232129817482790e-09);
    pc = __builtin_fma(z, pc, -2.75573143513906633035e-07);
    pc = __builtin_fma(z, pc,  2.48015872894767294178e-05);
    pc = __builtin_fma(z, pc, -1.38888888888741095749e-03);
    pc = __builtin_fma(z, pc,  4.16666666666666019037e-02);
    const double hz = 0.5 * z;
    const double w1 = 1.0 - hz;
    const double cv = w1 + (((1.0 - w1) - hz) + z * (z * pc)); // fdlibm careful form
    const int n = ((int)fn) & 3;
    const float S = (float)sv, C = (float)cv;
    const bool sw = (n & 1) != 0;
    const float sa = sw ? C : S;                 // n=0:(S,C) 1:(C,-S) 2:(-S,-C) 3:(-C,S)
    const float ca = sw ? S : C;
    sf = (n & 2) ? -sa : sa;
    cf = ((n + 1) & 2) ? -ca : ca;
}

// Rare decision-directed slow path (R5 verbatim): 16-point argmin + jax
// tie-average. noinline keeps ~200 instrs out of the 8x-unrolled hot body.
static __device__ __attribute__((noinline)) float2 dd_slow(float zre, float zim) {
#pragma clang fp contract(off)
    const double s10 = sqrt(10.0);
    float Lf[4];
    Lf[0] = (float)(-3.0 / s10); Lf[1] = (float)(-1.0 / s10);
    Lf[2] = (float)( 1.0 / s10); Lf[3] = (float)( 3.0 / s10);
    float dv[16], rv[16], wres[16], wims[16];
    float dmin = __builtin_inff();
#pragma unroll
    for (int k = 0; k < 16; ++k) {
        const float wre = zre - Lf[k >> 2];
        const float wim = zim - Lf[k & 3];
        const float r = crhypotf(wre, wim);
        const float d = r * r;
        wres[k] = wre; wims[k] = wim; rv[k] = r; dv[k] = d;
        dmin = fminf(dmin, d);
    }
    int cnt = 0;
#pragma unroll
    for (int k = 0; k < 16; ++k) cnt += (dv[k] == dmin) ? 1 : 0;
    float A, B;
    if (cnt == 1) {
        int j = 0;
#pragma unroll
        for (int k = 0; k < 16; ++k) if (dv[k] == dmin) j = k;
        A = 2.0f * wres[j];
        B = -(2.0f * wims[j]);
    } else {
        const float ctd = 1.0f / (float)cnt;
        float sa = 0.0f, sb = 0.0f;
#pragma unroll
        for (int k = 0; k < 16; ++k) {
            if (dv[k] == dmin) {
                const float ctr  = (2.0f * rv[k]) * ctd;
                const float ctm2 = ctr / rv[k];
                sa += (ctm2 * wres[k]);
                sb += -(ctm2 * wims[k]);
            }
        }
        A = sa; B = sb;
    }
    return make_float2(A, B);
}

// phi-chain only: advance phi by one PLL step (bit-identical ops/order to R5).
template<bool PILOT>
static __device__ __forceinline__ void phi_step(
    float yre, float yim, float txr, float txi,
    float Kv, const float* Lf, float& phi)
{
#pragma clang fp contract(off)
    const float QTHf = 0.63245553203367588f;     // bisector 2/sqrt(10)
    float s, c;
    cr_sincosf_nb((double)phi, s, c);
    const float zre = (yre * c) - (yim * s);
    const float zim = (yre * s) + (yim * c);
    float A, B;
    if (PILOT) {
        const float wre = zre - txr;
        const float wim = zim - txi;
        A = 2.0f * wre;
        B = -(2.0f * wim);
    } else {
        // fast path, always computed (bit-equal to literal path off-band, proven)
        const float tr = (zre < 0.0f) ? ((zre < -QTHf) ? Lf[0] : Lf[1])
                                      : ((zre <  QTHf) ? Lf[2] : Lf[3]);
        const float ti = (zim < 0.0f) ? ((zim < -QTHf) ? Lf[0] : Lf[1])
                                      : ((zim <  QTHf) ? Lf[2] : Lf[3]);
        const float wre0 = zre - tr;
        const float wim0 = zim - ti;
        A = 2.0f * wre0;
        B = -(2.0f * wim0);
        const float ar = fabsf(zre), ai = fabsf(zim);
        const float mr = fminf(fabsf(ar - QTHf), ar);
        const float mi = fminf(fabsf(ai - QTHf), ai);
        const bool slow = !(mr > 1e-4f && mi > 1e-4f);
        if (__builtin_expect(__ballot(slow) != 0ULL, 0)) {
            if (slow) { const float2 ab = dd_slow(zre, zim); A = ab.x; B = ab.y; }
        }
    }
    // ct_e = mul(ct_z, y); ct_v = mul(ct_e, e); gk = -Im(ct_v)
    const float ct_e_re = (A * yre) - (B * yim);
    const float ct_e_im = (A * yim) + (B * yre);
    const float ct_v_im = (ct_e_re * s) + (ct_e_im * c);
    const float gk = -ct_v_im;
    phi = phi - (Kv * gk);
}

// Serial kernel: ONLY the phi recurrence + raw-phase store, MODE-MAJOR
// (th_T[m*NSYMB + t]) so the downstream scan can vector-load contiguously.
// Active write set = 64 lines/CU -> L2 write-combines; store cost unchanged.
__global__ __launch_bounds__(64)
void ddpll_seq(const float* __restrict__ ei_re,
               const float* __restrict__ ei_im,
               const float* __restrict__ tx_re,
               const float* __restrict__ tx_im,
               const float* __restrict__ eta,
               float* __restrict__ out)
{
#pragma clang fp contract(off)
    const int m = blockIdx.x * 64 + threadIdx.x;   // mode 0..255
    const float Kv = (float)tanh((double)eta[0]);  // CR f32 tanh

    const double s10 = sqrt(10.0);
    float Lf[4];
    Lf[0] = (float)(-3.0 / s10); Lf[1] = (float)(-1.0 / s10);
    Lf[2] = (float)( 1.0 / s10); Lf[3] = (float)( 3.0 / s10);

    float phi = 0.0f;
    float* __restrict__ th_p = out + (size_t)m * NSYMB;   // mode-major raw th

    // ================= phase 1: pilot (t < LEAD) =================
    float pyr[UF], pyi[UF], pxr[UF], pxi[UF];
#pragma unroll
    for (int j = 0; j < UF; ++j) {
        const int idx = j * NMODES + m;
        pyr[j] = ei_re[idx]; pyi[j] = ei_im[idx];
        pxr[j] = tx_re[idx]; pxi[j] = tx_im[idx];
    }
    for (int tb = 0; tb < LEAD; tb += UF) {
        float yr[UF], yi[UF], xr[UF], xi[UF];
#pragma unroll
        for (int j = 0; j < UF; ++j) { yr[j]=pyr[j]; yi[j]=pyi[j]; xr[j]=pxr[j]; xi[j]=pxi[j]; }
        const int nb = tb + UF;
        // branchless prefetch: rows LEAD..LEAD+UF-1 are valid memory
#pragma unroll
        for (int j = 0; j < UF; ++j) {
            const int idx = (nb + j) * NMODES + m;
            pyr[j] = ei_re[idx]; pyi[j] = ei_im[idx];
            pxr[j] = tx_re[idx]; pxi[j] = tx_im[idx];
        }
#pragma unroll
        for (int j = 0; j < UF; ++j) {
            th_p[tb + j] = phi;                      // raw pre-update phase
            phi_step<true>(yr[j], yi[j], xr[j], xi[j], Kv, Lf, phi);
        }
    }

    // ================= phase 2: decision-directed =================
#pragma unroll
    for (int j = 0; j < UF; ++j) {
        const int idx = (LEAD + j) * NMODES + m;
        pyr[j] = ei_re[idx]; pyi[j] = ei_im[idx];
    }
    for (int tb = LEAD; tb < NSYMB; tb += UF) {
        float yr[UF], yi[UF];
#pragma unroll
        for (int j = 0; j < UF; ++j) { yr[j]=pyr[j]; yi[j]=pyi[j]; }
        const int nb = tb + UF;
#pragma unroll
        for (int j = 0; j < UF; ++j) {               // branchless prefetch, clamped
            const int tt = (nb + j < NSYMB) ? (nb + j) : (NSYMB - 1);
            const int idx = tt * NMODES + m;
            pyr[j] = ei_re[idx]; pyi[j] = ei_im[idx];
        }
#pragma unroll
        for (int j = 0; j < UF; ++j) {
            th_p[tb + j] = phi;
            phi_step<false>(yr[j], yi[j], 0.0f, 0.0f, Kv, Lf, phi);
        }
    }
}

// Parallel unwrap-correction on the mode-major layout: g = m*NSYMB + t.
// Reads th_T[g], th_T[g-1] (coalesced), writes c_T[g] (coalesced).
// Identical f32/f64 ops as the original in-loop unwrap, on identical th bits.
__global__ __launch_bounds__(256)
void ddpll_unwrapc(const float* __restrict__ thT, float* __restrict__ cT)
{
#pragma clang fp contract(off)
    const float P2f = 1.57079632679489661923f;   // f32(pi/2)
    const float P4f = 0.78539816339744830961f;   // f32(pi/4)
    const int g = blockIdx.x * 256 + threadIdx.x;
    const int m = g / NSYMB;
    const int t = g - m * NSYMB;
    float cv = 0.0f;                              // t==0: no correction
    if (t > 0) {
        const float thv  = thT[g];
        const float prev = thT[g - 1];
        const float dd = thv - prev;
        float rm = fmod_p2_exact(dd + P4f);
        rm = (rm < 0.0f) ? rm + P2f : rm;        // numpy floor-mod
        float ddmod = rm - P4f;
        ddmod = (ddmod == -P4f && dd > 0.0f) ? P4f : ddmod;
        const bool take = !(fabsf(dd) < P4f);
        cv = take ? (ddmod - dd) : 0.0f;
    }
    cT[g] = cv;
}

// Serial scan over mode-major rows: float4 loads (16 in flight), 32 t per
// iteration, stores to the FINAL theta[t][m] layout (lane-coalesced).
// cum fold order identical (adding +0.0f is the identity on cum).
__global__ __launch_bounds__(64)
void ddpll_scan(const float* __restrict__ thT, const float* __restrict__ cT,
                float* __restrict__ theta)
{
#pragma clang fp contract(off)
    const int m = blockIdx.x * 64 + threadIdx.x;   // mode 0..255
    const float4* __restrict__ pth = (const float4*)(thT + (size_t)m * NSYMB);
    const float4* __restrict__ pcv = (const float4*)(cT  + (size_t)m * NSYMB);
    float cum = 0.0f;
    float4 bth[8], bcv[8];
#pragma unroll
    for (int j = 0; j < 8; ++j) { bth[j] = pth[j]; bcv[j] = pcv[j]; }
    for (int tb = 0; tb < NSYMB; tb += 32) {
        float4 th_[8], cv_[8];
#pragma unroll
        for (int j = 0; j < 8; ++j) { th_[j] = bth[j]; cv_[j] = bcv[j]; }
        const int nb4 = (tb + 32) >> 2;            // next block, float4 index
        // unconditional prefetch: final overread (<=32 floats) of the last
        // mode lands in the adjacent c_T/theta regions of the same out buffer
#pragma unroll
        for (int j = 0; j < 8; ++j) { bth[j] = pth[nb4 + j]; bcv[j] = pcv[nb4 + j]; }
#pragma unroll
        for (int j = 0; j < 8; ++j) {
#pragma unroll
            for (int k = 0; k < 4; ++k) {
                const float cc = (&cv_[j].x)[k];
                const float tt = (&th_[j].x)[k];
                cum = cum + cc;                     // == original conditional update
                theta[(tb + j * 4 + k) * NMODES + m] = tt + cum;
            }
        }
    }
}

// Parallel epilogue: Eo = Ei * exp(i * theta_unwrapped)  (err ~1e-6 << thr)
__global__ __launch_bounds__(256)
void ddpll_rot(const float* __restrict__ ei_re,
               const float* __restrict__ ei_im,
               float* __restrict__ out)
{
    const int idx = blockIdx.x * 256 + threadIdx.x;
    const float U = out[(size_t)2 * NM + idx];
    float su, cu;
    sincosf(U, &su, &cu);
    const float yre = ei_re[idx], yim = ei_im[idx];
    out[2 * idx]     = (yre * cu) - (yim * su);
    out[2 * idx + 1] = (yre * su) + (yim * cu);
}

extern "C" void kernel_launch(void* const* d_in, const int* in_sizes, int n_in,
                              void* d_out, int out_size, void* d_ws, size_t ws_size,
                              hipStream_t stream)
{
    (void)in_sizes; (void)n_in; (void)out_size; (void)d_ws; (void)ws_size;
    const float* ei_re = (const float*)d_in[0];
    const float* ei_im = (const float*)d_in[1];
    float* out = (float*)d_out;
    float* thT = out;                 // [0,   NM): mode-major raw phase
    float* cT  = out + (size_t)NM;    // [NM, 2NM): mode-major corrections
    float* th  = out + (size_t)2 * NM;// [2NM,3NM): final theta [t][m]
    // rot overwrites [0,2NM) with Eo only after scan consumed thT/cT.

    ddpll_seq<<<dim3(NMODES / 64), dim3(64), 0, stream>>>(
        ei_re, ei_im,
        (const float*)d_in[2],
        (const float*)d_in[3],
        (const float*)d_in[4],
        out);
    ddpll_unwrapc<<<dim3(NM / 256), dim3(256), 0, stream>>>(thT, cT);
    ddpll_scan<<<dim3(NMODES / 64), dim3(64), 0, stream>>>(thT, cT, th);
    ddpll_rot<<<dim3(NM / 256), dim3(256), 0, stream>>>(ei_re, ei_im, out);
}